// Round 6
// baseline (481.951 us; speedup 1.0000x reference)
//
#include <hip/hip_runtime.h>
#include <hip/hip_bf16.h>
#include <math.h>

// B=8, N=32, S=512, H=768, K=3, C=128, L=64, W=16
#define NEG_INF (-1e30f)

typedef _Float16 half8 __attribute__((ext_vector_type(8)));
typedef _Float16 half4 __attribute__((ext_vector_type(4)));
typedef float f32x4 __attribute__((ext_vector_type(4)));

// ---------------------------------------------------------------------------
// Kernel 1 (prep):
//   A2 [4096 x 2304] f16 = [A_hi | A_lo*2^6 | A_hi*2^-6]  (4 elems/thread)
//   Bt [1152 x 2304] f16 (j-major) = [B_hi | B_hi*2^-6 | B_lo*2^6]
//   fcT[i][c] fp32
//   blocks: [0,3072) A2 | [3072,3216) Bt | [3216,3312) fcT
// ---------------------------------------------------------------------------
__global__ __launch_bounds__(256) void prep(
    const float* __restrict__ tokens, const float* __restrict__ span_w,
    const float* __restrict__ prefix_w, const float* __restrict__ suffix_w,
    const float* __restrict__ fc_w, _Float16* __restrict__ A2,
    _Float16* __restrict__ Bt, float* __restrict__ fcT) {
  int bid = blockIdx.x;
  int t = threadIdx.x;
  if (bid < 3072) {  // A2: 4 consecutive h per thread
    int g4 = (bid * 256 + t) * 4;  // m*768 + h, h%4==0
    int m = g4 / 768, h = g4 % 768;
    float4 x = *(const float4*)(tokens + g4);
    float xs[4] = {x.x, x.y, x.z, x.w};
    half4 hi, lo, hi6;
#pragma unroll
    for (int i = 0; i < 4; ++i) {
      _Float16 h_ = (_Float16)xs[i];
      hi[i] = h_;
      lo[i] = (_Float16)((xs[i] - (float)h_) * 64.0f);
      hi6[i] = (_Float16)((float)h_ * 0.015625f);
    }
    size_t base = (size_t)m * 2304 + h;
    *(half4*)(A2 + base) = hi;
    *(half4*)(A2 + base + 768) = lo;
    *(half4*)(A2 + base + 1536) = hi6;
  } else if (bid < 3216) {  // Bt: 8 h x 3 taps per thread, coalesced
    int g = (bid - 3072) * 256 + t;  // over 3*128*96 = 36864
    int ws = g / 12288;
    int r = g % 12288;
    int c = r / 96, h = (r % 96) * 8;
    const float* wsrc = (ws == 0) ? prefix_w : (ws == 1) ? span_w : suffix_w;
    const float* src = wsrc + (size_t)(c * 768 + h) * 3;  // 24 floats
    float wv[24];
#pragma unroll
    for (int i = 0; i < 6; ++i) *(float4*)&wv[i * 4] = *(const float4*)(src + i * 4);
#pragma unroll
    for (int tap = 0; tap < 3; ++tap) {
      half8 hi, lo, hi6;
#pragma unroll
      for (int i = 0; i < 8; ++i) {
        float x = wv[i * 3 + tap];
        _Float16 h_ = (_Float16)x;
        hi[i] = h_;
        lo[i] = (_Float16)((x - (float)h_) * 64.0f);
        hi6[i] = (_Float16)((float)h_ * 0.015625f);
      }
      size_t jb = (size_t)(ws * 384 + tap * 128 + c) * 2304 + h;
      *(half8*)(Bt + jb) = hi;
      *(half8*)(Bt + jb + 768) = hi6;
      *(half8*)(Bt + jb + 1536) = lo;
    }
  } else {  // fcT
    int g = (bid - 3216) * 256 + t;  // i*64 + c, 24576 total
    int i = g >> 6, c = g & 63;
    fcT[g] = fc_w[c * 384 + i];
  }
}

// ---------------------------------------------------------------------------
// Kernel 2: MFMA GEMM  Ct[j][m] = sum_k A2[m][k] * Bt[j][k]   (fp32 out)
//   M=4096, N=1152, K=2304. BM=128, BN=64, BK=64, 512 thr (8 waves).
//   Wave tile 32x32 (2x2 mfma_16x16x32). Register-staged 2-deep pipeline:
//   tile i+2 loaded to VGPRs at iter i, ds_written to spare buffer at end
//   of iter i, consumed at iter i+2 -> load latency covered by ~2 iters.
//   LDS rows = 64 halfs; 16B chunks XOR-swizzled (chunk ^ row&7): staging
//   ds_writes conflict-free, fragment ds_read_b128 spread over all banks.
// ---------------------------------------------------------------------------
__global__ __launch_bounds__(512) void gemm_f16(const _Float16* __restrict__ A2,
                                                const _Float16* __restrict__ Bt,
                                                float* __restrict__ Ct) {
  __shared__ _Float16 As[2][128 * 64];  // 2 x 16 KB
  __shared__ _Float16 Bs[2][64 * 64];   // 2 x 8 KB
  const int bm = blockIdx.x * 128;
  const int bj = blockIdx.y * 64;
  const int tid = threadIdx.x;
  const int w = tid >> 6;
  const int lane = tid & 63;
  // staging: thread -> (row sr, chunk sc); consecutive tid = consecutive 16B
  const int sr = tid >> 3;  // 0..63
  const int sc = tid & 7;   // 16B chunk 0..7
  const _Float16* gA0 = A2 + (size_t)(bm + sr) * 2304 + sc * 8;
  const _Float16* gA1 = A2 + (size_t)(bm + 64 + sr) * 2304 + sc * 8;
  const _Float16* gB = Bt + (size_t)(bj + sr) * 2304 + sc * 8;
  const int swz = (sc ^ (sr & 7)) * 8;
  const int wa0 = sr * 64 + swz;
  const int wa1 = (64 + sr) * 64 + swz;  // (64+sr)&7 == sr&7
  const int wb = sr * 64 + swz;
  // compute indices
  const int mrow = lane & 15;
  const int qb = lane >> 4;
  const int m0w = (w & 3) * 32;
  const int n0w = (w >> 2) * 32;
  const int co0 = (qb ^ (lane & 7)) * 8;
  const int co1 = ((qb + 4) ^ (lane & 7)) * 8;
  f32x4 acc[2][2];
#pragma unroll
  for (int i = 0; i < 2; ++i)
#pragma unroll
    for (int j = 0; j < 2; ++j) acc[i][j] = (f32x4){0.f, 0.f, 0.f, 0.f};

  half8 pA0[2], pA1[2], pB[2];  // reg set s holds tile t with t&1==s
  // prologue: tile0 -> LDS buf0 (via regs), tile1 -> reg set1
  pA0[0] = *(const half8*)(gA0);
  pA1[0] = *(const half8*)(gA1);
  pB[0] = *(const half8*)(gB);
  pA0[1] = *(const half8*)(gA0 + 64);
  pA1[1] = *(const half8*)(gA1 + 64);
  pB[1] = *(const half8*)(gB + 64);
  *(half8*)&As[0][wa0] = pA0[0];
  *(half8*)&As[0][wa1] = pA1[0];
  *(half8*)&Bs[0][wb] = pB[0];

  for (int i = 0; i < 36; ++i) {
    const int cur = i & 1;
    __syncthreads();  // buf cur holds tile i; prev iter's reads done
    if (i + 2 < 36) {  // load tile i+2 into reg set cur ((i+2)&1 == cur)
      const int k = (i + 2) * 64;
      pA0[cur] = *(const half8*)(gA0 + k);
      pA1[cur] = *(const half8*)(gA1 + k);
      pB[cur] = *(const half8*)(gB + k);
    }
#pragma unroll
    for (int ks = 0; ks < 2; ++ks) {
      const int co = ks ? co1 : co0;
      half8 a0 = *(const half8*)&As[cur][(m0w + mrow) * 64 + co];
      half8 a1 = *(const half8*)&As[cur][(m0w + 16 + mrow) * 64 + co];
      half8 b0 = *(const half8*)&Bs[cur][(n0w + mrow) * 64 + co];
      half8 b1 = *(const half8*)&Bs[cur][(n0w + 16 + mrow) * 64 + co];
      acc[0][0] = __builtin_amdgcn_mfma_f32_16x16x32_f16(a0, b0, acc[0][0], 0, 0, 0);
      acc[1][0] = __builtin_amdgcn_mfma_f32_16x16x32_f16(a1, b0, acc[1][0], 0, 0, 0);
      acc[0][1] = __builtin_amdgcn_mfma_f32_16x16x32_f16(a0, b1, acc[0][1], 0, 0, 0);
      acc[1][1] = __builtin_amdgcn_mfma_f32_16x16x32_f16(a1, b1, acc[1][1], 0, 0, 0);
    }
    if (i + 1 < 36) {  // stage tile i+1 (reg set cur^1) into buf cur^1
      const int nb = cur ^ 1;
      *(half8*)&As[nb][wa0] = pA0[nb];
      *(half8*)&As[nb][wa1] = pA1[nb];
      *(half8*)&Bs[nb][wb] = pB[nb];
    }
  }
  // C/D layout: m = (lane>>4)*4 + reg, n = lane&15
  const int mbase = bm + m0w + qb * 4;
#pragma unroll
  for (int mt = 0; mt < 2; ++mt)
#pragma unroll
    for (int nt = 0; nt < 2; ++nt) {
      int n_out = bj + n0w + nt * 16 + mrow;
      *(f32x4*)(Ct + (size_t)n_out * 4096 + mbase + mt * 16) = acc[mt][nt];
    }
}

// ---------------------------------------------------------------------------
// Kernel 3: per-(b,c) tap-combine + prefix-max / suffix-max scans
//   256 threads = 4 independent wave-scans; 256 blocks.
// ---------------------------------------------------------------------------
__global__ __launch_bounds__(256) void scan_kernel(const float* __restrict__ Ct,
                                                   const int* __restrict__ wsl,
                                                   float* __restrict__ PM2,
                                                   float* __restrict__ SM2) {
  int pair = blockIdx.x * 4 + (threadIdx.x >> 6);
  int b = pair >> 7;
  int c = pair & 127;
  int lane = threadIdx.x & 63;
  int mb = b * 512;
  int t0 = lane * 8;
  const float* p0 = Ct + (size_t)(0 + c) * 4096 + mb;
  const float* p1 = Ct + (size_t)(128 + c) * 4096 + mb;
  const float* p2 = Ct + (size_t)(256 + c) * 4096 + mb;
  float v[8];
#pragma unroll
  for (int i = 0; i < 8; i++) {
    int t = t0 + i;
    v[i] = (t < 494) ? (p0[t] + p1[t + 1] + p2[t + 2]) : NEG_INF;
  }
#pragma unroll
  for (int i = 1; i < 8; i++) v[i] = fmaxf(v[i], v[i - 1]);
  float x = v[7];
#pragma unroll
  for (int d = 1; d < 64; d <<= 1) {
    float y = __shfl_up(x, d);
    if (lane >= d) x = fmaxf(x, y);
  }
  float excl = __shfl_up(x, 1);
  if (lane == 0) excl = NEG_INF;
  float* pm = PM2 + (size_t)pair * 512;
#pragma unroll
  for (int i = 0; i < 8; i++) {
    int t = t0 + i;
    if (t < 494) pm[t] = fmaxf(v[i], excl);
  }
  const float* s0 = Ct + (size_t)(768 + c) * 4096 + mb;
  const float* s1 = Ct + (size_t)(896 + c) * 4096 + mb;
  const float* s2 = Ct + (size_t)(1024 + c) * 4096 + mb;
  int qmax = wsl[b] - 3;
  if (qmax > 509) qmax = 509;
  float u[8];
#pragma unroll
  for (int i = 0; i < 8; i++) {
    int q = t0 + i;
    u[i] = (q <= qmax) ? (s0[q] + s1[q + 1] + s2[q + 2]) : NEG_INF;
  }
#pragma unroll
  for (int i = 6; i >= 0; i--) u[i] = fmaxf(u[i], u[i + 1]);
  float xr = u[0];
#pragma unroll
  for (int d = 1; d < 64; d <<= 1) {
    float y = __shfl_down(xr, d);
    if (lane < 64 - d) xr = fmaxf(xr, y);
  }
  float exclr = __shfl_down(xr, 1);
  if (lane == 63) exclr = NEG_INF;
  float* sm = SM2 + (size_t)pair * 512;
#pragma unroll
  for (int i = 0; i < 8; i++) sm[t0 + i] = fmaxf(u[i], exclr);
}

// ---------------------------------------------------------------------------
// Kernel 4: per-span features + coalesced FC + sigmoid + threshold
// ---------------------------------------------------------------------------
__global__ __launch_bounds__(128) void span_kernel(
    const float* __restrict__ Ct, const float* __restrict__ PM2,
    const float* __restrict__ SM2, const float* __restrict__ prefix_b,
    const float* __restrict__ span_b, const float* __restrict__ suffix_b,
    const float* __restrict__ fcT, const float* __restrict__ fc_b,
    const int* __restrict__ spans, const int* __restrict__ wsl,
    float* __restrict__ out) {
  __shared__ float sfeat[384];
  __shared__ float part[64];
  int sp = blockIdx.x;
  int b = sp >> 5;
  int c = threadIdx.x;
  int s = spans[sp * 2], e = spans[sp * 2 + 1];
  int Lb = wsl[b];
  int mb = b * 512;
  {  // prefix window (T=496)
    const float* t0p = Ct + (size_t)c * 4096 + mb;
    const float* t1p = Ct + (size_t)(128 + c) * 4096 + mb;
    float m = NEG_INF;
    if (s >= 3) m = fmaxf(m, PM2[(size_t)(b * 128 + c) * 512 + s - 3]);
    if (s >= 2 && s <= 495) m = fmaxf(m, t0p[s - 2] + t1p[s - 1]);
    if (s >= 1 && s <= 494) m = fmaxf(m, t0p[s - 1]);
    if (s <= 493) m = fmaxf(m, 0.0f);
    sfeat[c] = m + prefix_b[c];
  }
  {  // span window (T=16)
    const float* u0 = Ct + (size_t)(384 + c) * 4096 + mb;
    const float* u1 = Ct + (size_t)(512 + c) * 4096 + mb;
    const float* u2 = Ct + (size_t)(640 + c) * 4096 + mb;
    int w = e - s;
    float m = NEG_INF;
    for (int p = 0; p + 2 < w; ++p)
      m = fmaxf(m, u0[s + p] + u1[s + p + 1] + u2[s + p + 2]);
    if (w >= 2 && w <= 15) m = fmaxf(m, u0[s + w - 2] + u1[s + w - 1]);
    if (w <= 14) m = fmaxf(m, u0[s + w - 1]);
    if (w <= 13) m = fmaxf(m, 0.0f);
    sfeat[128 + c] = m + span_b[c];
  }
  {  // suffix window (T=511)
    const float* x0 = Ct + (size_t)(768 + c) * 4096 + mb;
    const float* x1 = Ct + (size_t)(896 + c) * 4096 + mb;
    float m = NEG_INF;
    if (e <= Lb - 3) m = fmaxf(m, SM2[(size_t)(b * 128 + c) * 512 + e]);
    if (Lb - 2 - e >= 0 && Lb - 2 - e <= 508)
      m = fmaxf(m, x0[Lb - 2] + x1[Lb - 1]);
    if (Lb - 1 - e >= 0 && Lb - 1 - e <= 508) m = fmaxf(m, x0[Lb - 1]);
    if (Lb - e <= 508) m = fmaxf(m, 0.0f);
    sfeat[256 + c] = m + suffix_b[c];
  }
  __syncthreads();
  {  // FC: out[c] = sigmoid(fc_b[c] + sum_i sfeat[i]*fcT[i][c])
    int cc = threadIdx.x & 63;
    int half = threadIdx.x >> 6;
    float acc2 = 0.0f;
    const float* fp = fcT + (size_t)(half * 192) * 64 + cc;
    const float* sf = sfeat + half * 192;
#pragma unroll 8
    for (int i = 0; i < 192; ++i) acc2 = fmaf(sf[i], fp[(size_t)i * 64], acc2);
    if (half) part[cc] = acc2;
    __syncthreads();
    if (!half) {
      float a = acc2 + part[cc] + fc_b[cc];
      float pr = 1.0f / (1.0f + expf(-a));
      out[sp * 64 + cc] = pr;
      out[16384 + sp * 64 + cc] = (pr > 0.5f) ? 1.0f : 0.0f;
    }
  }
}

// ---------------------------------------------------------------------------
extern "C" void kernel_launch(void* const* d_in, const int* in_sizes, int n_in,
                              void* d_out, int out_size, void* d_ws,
                              size_t ws_size, hipStream_t stream) {
  const float* tokens = (const float*)d_in[0];
  const float* span_w = (const float*)d_in[1];
  const float* span_b = (const float*)d_in[2];
  const float* prefix_w = (const float*)d_in[3];
  const float* prefix_b = (const float*)d_in[4];
  const float* suffix_w = (const float*)d_in[5];
  const float* suffix_b = (const float*)d_in[6];
  const float* fc_w = (const float*)d_in[7];
  const float* fc_b = (const float*)d_in[8];
  const int* spans = (const int*)d_in[9];
  const int* wsl = (const int*)d_in[10];
  float* out = (float*)d_out;

  char* ws = (char*)d_ws;
  float* Ct = (float*)ws;                     // 1152*4096*4 = 18874368
  _Float16* A2 = (_Float16*)(ws + 18874368);  // 4096*2304*2 = 18874368
  _Float16* Bt = (_Float16*)(ws + 37748736);  // 1152*2304*2 =  5308416
  float* PM2 = (float*)(ws + 43057152);       // 8*128*512*4 =  2097152
  float* SM2 = (float*)(ws + 45154304);       //                2097152
  float* fcT = (float*)(ws + 47251456);       // 384*64*4    =    98304

  hipLaunchKernelGGL(prep, dim3(3312), dim3(256), 0, stream, tokens, span_w,
                     prefix_w, suffix_w, fc_w, A2, Bt, fcT);
  hipLaunchKernelGGL(gemm_f16, dim3(32, 18), dim3(512), 0, stream, A2, Bt, Ct);
  hipLaunchKernelGGL(scan_kernel, dim3(256), dim3(256), 0, stream, Ct, wsl,
                     PM2, SM2);
  hipLaunchKernelGGL(span_kernel, dim3(256), dim3(128), 0, stream, Ct, PM2,
                     SM2, prefix_b, span_b, suffix_b, fcT, fc_b, spans, wsl,
                     out);
}

// Round 7
// 153.156 us; speedup vs baseline: 3.1468x; 3.1468x over previous
//
#include <hip/hip_runtime.h>
#include <hip/hip_bf16.h>
#include <math.h>

// B=8, N=32, S=512, H=768, K=3, C=128, L=64, W=16
#define NEG_INF (-1e30f)

typedef _Float16 half8 __attribute__((ext_vector_type(8)));
typedef _Float16 half4 __attribute__((ext_vector_type(4)));
typedef float f32x4 __attribute__((ext_vector_type(4)));

// ---------------------------------------------------------------------------
// Kernel 1 (prep):
//   A2 [4096 x 2304] f16 = [A_hi | A_lo*2^6 | A_hi*2^-6]  (4 elems/thread)
//   Bt [1152 x 2304] f16 (j-major) = [B_hi | B_hi*2^-6 | B_lo*2^6]
//   fcT[i][c] fp32
// ---------------------------------------------------------------------------
__global__ __launch_bounds__(256) void prep(
    const float* __restrict__ tokens, const float* __restrict__ span_w,
    const float* __restrict__ prefix_w, const float* __restrict__ suffix_w,
    const float* __restrict__ fc_w, _Float16* __restrict__ A2,
    _Float16* __restrict__ Bt, float* __restrict__ fcT) {
  int bid = blockIdx.x;
  int t = threadIdx.x;
  if (bid < 3072) {  // A2
    int g4 = (bid * 256 + t) * 4;
    int m = g4 / 768, h = g4 % 768;
    float4 x = *(const float4*)(tokens + g4);
    float xs[4] = {x.x, x.y, x.z, x.w};
    half4 hi, lo, hi6;
#pragma unroll
    for (int i = 0; i < 4; ++i) {
      _Float16 h_ = (_Float16)xs[i];
      hi[i] = h_;
      lo[i] = (_Float16)((xs[i] - (float)h_) * 64.0f);
      hi6[i] = (_Float16)((float)h_ * 0.015625f);
    }
    size_t base = (size_t)m * 2304 + h;
    *(half4*)(A2 + base) = hi;
    *(half4*)(A2 + base + 768) = lo;
    *(half4*)(A2 + base + 1536) = hi6;
  } else if (bid < 3216) {  // Bt
    int g = (bid - 3072) * 256 + t;  // over 3*128*96 = 36864
    int ws = g / 12288;
    int r = g % 12288;
    int c = r / 96, h = (r % 96) * 8;
    const float* wsrc = (ws == 0) ? prefix_w : (ws == 1) ? span_w : suffix_w;
    const float* src = wsrc + (size_t)(c * 768 + h) * 3;
    float wv[24];
#pragma unroll
    for (int i = 0; i < 6; ++i) *(float4*)&wv[i * 4] = *(const float4*)(src + i * 4);
#pragma unroll
    for (int tap = 0; tap < 3; ++tap) {
      half8 hi, lo, hi6;
#pragma unroll
      for (int i = 0; i < 8; ++i) {
        float x = wv[i * 3 + tap];
        _Float16 h_ = (_Float16)x;
        hi[i] = h_;
        lo[i] = (_Float16)((x - (float)h_) * 64.0f);
        hi6[i] = (_Float16)((float)h_ * 0.015625f);
      }
      size_t jb = (size_t)(ws * 384 + tap * 128 + c) * 2304 + h;
      *(half8*)(Bt + jb) = hi;
      *(half8*)(Bt + jb + 768) = hi6;
      *(half8*)(Bt + jb + 1536) = lo;
    }
  } else {  // fcT
    int g = (bid - 3216) * 256 + t;
    int i = g >> 6, c = g & 63;
    fcT[g] = fc_w[c * 384 + i];
  }
}

// ---------------------------------------------------------------------------
// Kernel 2: MFMA GEMM  Ct[j][m] = sum_k A2[m][k] * Bt[j][k]
//   M=4096, N=1152, K=2304. BM=128, BN=128, BK=64, 512 thr (8 waves).
//   Grid (32,9)=288: staging traffic 332 MB (vs 510 at BN=64) — the r5/r6
//   counters showed staging-BW queue is the binding resource.
//   2-deep register pipeline, loop body EXPLICITLY duplicated (cur=0/1) so
//   no dynamic register-array indexing (r6's scratch-spill disaster).
//   XOR-swizzled LDS rows (conflict-free, verified r5).
// ---------------------------------------------------------------------------
__global__ __launch_bounds__(512) void gemm_f16(const _Float16* __restrict__ A2,
                                                const _Float16* __restrict__ Bt,
                                                float* __restrict__ Ct) {
  __shared__ _Float16 As[2][128 * 64];  // 2 x 16 KB
  __shared__ _Float16 Bs[2][128 * 64];  // 2 x 16 KB
  const int bm = blockIdx.x * 128;
  const int bj = blockIdx.y * 128;
  const int tid = threadIdx.x;
  const int w = tid >> 6;
  const int lane = tid & 63;
  // staging: 1024 16B-chunks per array; thread handles chunks tid and tid+512
  const int r0 = tid >> 3, c0 = tid & 7;
  const int r1 = (tid + 512) >> 3, c1 = tid & 7;  // (tid+512)&7 == tid&7
  const _Float16* gA0 = A2 + (size_t)(bm + r0) * 2304 + c0 * 8;
  const _Float16* gA1 = A2 + (size_t)(bm + r1) * 2304 + c1 * 8;
  const _Float16* gB0 = Bt + (size_t)(bj + r0) * 2304 + c0 * 8;
  const _Float16* gB1 = Bt + (size_t)(bj + r1) * 2304 + c1 * 8;
  const int wa0 = r0 * 64 + ((c0 ^ (r0 & 7)) * 8);
  const int wa1 = r1 * 64 + ((c1 ^ (r1 & 7)) * 8);
  // compute indices: wave tile 32(m) x 64(n)
  const int mrow = lane & 15;
  const int qb = lane >> 4;
  const int m0w = (w & 3) * 32;
  const int n0w = (w >> 2) * 64;
  const int co0 = (qb ^ (lane & 7)) * 8;
  const int co1 = ((qb + 4) ^ (lane & 7)) * 8;
  f32x4 acc[2][4];
#pragma unroll
  for (int i = 0; i < 2; ++i)
#pragma unroll
    for (int j = 0; j < 4; ++j) acc[i][j] = (f32x4){0.f, 0.f, 0.f, 0.f};

  half8 sA0a, sA1a, sB0a, sB1a;  // reg set A (even tiles' prefetch)
  half8 sA0b, sA1b, sB0b, sB1b;  // reg set B (odd tiles' prefetch)
  // prologue: tile0 -> regs -> buf0; tile1 -> reg set B
  sA0a = *(const half8*)(gA0);
  sA1a = *(const half8*)(gA1);
  sB0a = *(const half8*)(gB0);
  sB1a = *(const half8*)(gB1);
  *(half8*)&As[0][wa0] = sA0a;
  *(half8*)&As[0][wa1] = sA1a;
  *(half8*)&Bs[0][wa0] = sB0a;
  *(half8*)&Bs[0][wa1] = sB1a;
  sA0b = *(const half8*)(gA0 + 64);
  sA1b = *(const half8*)(gA1 + 64);
  sB0b = *(const half8*)(gB0 + 64);
  sB1b = *(const half8*)(gB1 + 64);

#define COMPUTE_HALF(BUF, CO)                                                  \
  {                                                                            \
    half8 a0 = *(const half8*)&As[BUF][(m0w + mrow) * 64 + (CO)];              \
    half8 a1 = *(const half8*)&As[BUF][(m0w + 16 + mrow) * 64 + (CO)];         \
    _Pragma("unroll") for (int nt = 0; nt < 4; ++nt) {                         \
      half8 b = *(const half8*)&Bs[BUF][(n0w + nt * 16 + mrow) * 64 + (CO)];   \
      acc[0][nt] =                                                             \
          __builtin_amdgcn_mfma_f32_16x16x32_f16(a0, b, acc[0][nt], 0, 0, 0);  \
      acc[1][nt] =                                                             \
          __builtin_amdgcn_mfma_f32_16x16x32_f16(a1, b, acc[1][nt], 0, 0, 0);  \
    }                                                                          \
  }

  for (int i = 0; i < 36; i += 2) {
    // ---- even iteration: consume buf0 (tile i), prefetch tile i+2 -> set A,
    //      stage set B (tile i+1) -> buf1
    __syncthreads();
    if (i + 2 < 36) {
      const int k = (i + 2) * 64;
      sA0a = *(const half8*)(gA0 + k);
      sA1a = *(const half8*)(gA1 + k);
      sB0a = *(const half8*)(gB0 + k);
      sB1a = *(const half8*)(gB1 + k);
    }
    COMPUTE_HALF(0, co0)
    COMPUTE_HALF(0, co1)
    *(half8*)&As[1][wa0] = sA0b;
    *(half8*)&As[1][wa1] = sA1b;
    *(half8*)&Bs[1][wa0] = sB0b;
    *(half8*)&Bs[1][wa1] = sB1b;
    // ---- odd iteration: consume buf1 (tile i+1), prefetch tile i+3 -> set B,
    //      stage set A (tile i+2) -> buf0
    __syncthreads();
    if (i + 3 < 36) {
      const int k = (i + 3) * 64;
      sA0b = *(const half8*)(gA0 + k);
      sA1b = *(const half8*)(gA1 + k);
      sB0b = *(const half8*)(gB0 + k);
      sB1b = *(const half8*)(gB1 + k);
    }
    COMPUTE_HALF(1, co0)
    COMPUTE_HALF(1, co1)
    if (i + 2 < 36) {
      *(half8*)&As[0][wa0] = sA0a;
      *(half8*)&As[0][wa1] = sA1a;
      *(half8*)&Bs[0][wa0] = sB0a;
      *(half8*)&Bs[0][wa1] = sB1a;
    }
  }
#undef COMPUTE_HALF

  // C/D layout: m = (lane>>4)*4 + reg, n = lane&15
  const int mbase = bm + m0w + qb * 4;
#pragma unroll
  for (int mt = 0; mt < 2; ++mt)
#pragma unroll
    for (int nt = 0; nt < 4; ++nt) {
      int n_out = bj + n0w + nt * 16 + mrow;
      *(f32x4*)(Ct + (size_t)n_out * 4096 + mbase + mt * 16) = acc[mt][nt];
    }
}

// ---------------------------------------------------------------------------
// Kernel 3: per-(b,c) tap-combine + prefix-max / suffix-max scans
// ---------------------------------------------------------------------------
__global__ __launch_bounds__(256) void scan_kernel(const float* __restrict__ Ct,
                                                   const int* __restrict__ wsl,
                                                   float* __restrict__ PM2,
                                                   float* __restrict__ SM2) {
  int pair = blockIdx.x * 4 + (threadIdx.x >> 6);
  int b = pair >> 7;
  int c = pair & 127;
  int lane = threadIdx.x & 63;
  int mb = b * 512;
  int t0 = lane * 8;
  const float* p0 = Ct + (size_t)(0 + c) * 4096 + mb;
  const float* p1 = Ct + (size_t)(128 + c) * 4096 + mb;
  const float* p2 = Ct + (size_t)(256 + c) * 4096 + mb;
  float v[8];
#pragma unroll
  for (int i = 0; i < 8; i++) {
    int t = t0 + i;
    v[i] = (t < 494) ? (p0[t] + p1[t + 1] + p2[t + 2]) : NEG_INF;
  }
#pragma unroll
  for (int i = 1; i < 8; i++) v[i] = fmaxf(v[i], v[i - 1]);
  float x = v[7];
#pragma unroll
  for (int d = 1; d < 64; d <<= 1) {
    float y = __shfl_up(x, d);
    if (lane >= d) x = fmaxf(x, y);
  }
  float excl = __shfl_up(x, 1);
  if (lane == 0) excl = NEG_INF;
  float* pm = PM2 + (size_t)pair * 512;
#pragma unroll
  for (int i = 0; i < 8; i++) {
    int t = t0 + i;
    if (t < 494) pm[t] = fmaxf(v[i], excl);
  }
  const float* s0 = Ct + (size_t)(768 + c) * 4096 + mb;
  const float* s1 = Ct + (size_t)(896 + c) * 4096 + mb;
  const float* s2 = Ct + (size_t)(1024 + c) * 4096 + mb;
  int qmax = wsl[b] - 3;
  if (qmax > 509) qmax = 509;
  float u[8];
#pragma unroll
  for (int i = 0; i < 8; i++) {
    int q = t0 + i;
    u[i] = (q <= qmax) ? (s0[q] + s1[q + 1] + s2[q + 2]) : NEG_INF;
  }
#pragma unroll
  for (int i = 6; i >= 0; i--) u[i] = fmaxf(u[i], u[i + 1]);
  float xr = u[0];
#pragma unroll
  for (int d = 1; d < 64; d <<= 1) {
    float y = __shfl_down(xr, d);
    if (lane < 64 - d) xr = fmaxf(xr, y);
  }
  float exclr = __shfl_down(xr, 1);
  if (lane == 63) exclr = NEG_INF;
  float* sm = SM2 + (size_t)pair * 512;
#pragma unroll
  for (int i = 0; i < 8; i++) sm[t0 + i] = fmaxf(u[i], exclr);
}

// ---------------------------------------------------------------------------
// Kernel 4: per-span features + coalesced FC + sigmoid + threshold
// ---------------------------------------------------------------------------
__global__ __launch_bounds__(128) void span_kernel(
    const float* __restrict__ Ct, const float* __restrict__ PM2,
    const float* __restrict__ SM2, const float* __restrict__ prefix_b,
    const float* __restrict__ span_b, const float* __restrict__ suffix_b,
    const float* __restrict__ fcT, const float* __restrict__ fc_b,
    const int* __restrict__ spans, const int* __restrict__ wsl,
    float* __restrict__ out) {
  __shared__ float sfeat[384];
  __shared__ float part[64];
  int sp = blockIdx.x;
  int b = sp >> 5;
  int c = threadIdx.x;
  int s = spans[sp * 2], e = spans[sp * 2 + 1];
  int Lb = wsl[b];
  int mb = b * 512;
  {  // prefix (T=496)
    const float* t0p = Ct + (size_t)c * 4096 + mb;
    const float* t1p = Ct + (size_t)(128 + c) * 4096 + mb;
    float m = NEG_INF;
    if (s >= 3) m = fmaxf(m, PM2[(size_t)(b * 128 + c) * 512 + s - 3]);
    if (s >= 2 && s <= 495) m = fmaxf(m, t0p[s - 2] + t1p[s - 1]);
    if (s >= 1 && s <= 494) m = fmaxf(m, t0p[s - 1]);
    if (s <= 493) m = fmaxf(m, 0.0f);
    sfeat[c] = m + prefix_b[c];
  }
  {  // span (T=16)
    const float* u0 = Ct + (size_t)(384 + c) * 4096 + mb;
    const float* u1 = Ct + (size_t)(512 + c) * 4096 + mb;
    const float* u2 = Ct + (size_t)(640 + c) * 4096 + mb;
    int w = e - s;
    float m = NEG_INF;
    for (int p = 0; p + 2 < w; ++p)
      m = fmaxf(m, u0[s + p] + u1[s + p + 1] + u2[s + p + 2]);
    if (w >= 2 && w <= 15) m = fmaxf(m, u0[s + w - 2] + u1[s + w - 1]);
    if (w <= 14) m = fmaxf(m, u0[s + w - 1]);
    if (w <= 13) m = fmaxf(m, 0.0f);
    sfeat[128 + c] = m + span_b[c];
  }
  {  // suffix (T=511)
    const float* x0 = Ct + (size_t)(768 + c) * 4096 + mb;
    const float* x1 = Ct + (size_t)(896 + c) * 4096 + mb;
    float m = NEG_INF;
    if (e <= Lb - 3) m = fmaxf(m, SM2[(size_t)(b * 128 + c) * 512 + e]);
    if (Lb - 2 - e >= 0 && Lb - 2 - e <= 508)
      m = fmaxf(m, x0[Lb - 2] + x1[Lb - 1]);
    if (Lb - 1 - e >= 0 && Lb - 1 - e <= 508) m = fmaxf(m, x0[Lb - 1]);
    if (Lb - e <= 508) m = fmaxf(m, 0.0f);
    sfeat[256 + c] = m + suffix_b[c];
  }
  __syncthreads();
  {
    int cc = threadIdx.x & 63;
    int half = threadIdx.x >> 6;
    float acc2 = 0.0f;
    const float* fp = fcT + (size_t)(half * 192) * 64 + cc;
    const float* sf = sfeat + half * 192;
#pragma unroll 8
    for (int i = 0; i < 192; ++i) acc2 = fmaf(sf[i], fp[(size_t)i * 64], acc2);
    if (half) part[cc] = acc2;
    __syncthreads();
    if (!half) {
      float a = acc2 + part[cc] + fc_b[cc];
      float pr = 1.0f / (1.0f + expf(-a));
      out[sp * 64 + cc] = pr;
      out[16384 + sp * 64 + cc] = (pr > 0.5f) ? 1.0f : 0.0f;
    }
  }
}

// ---------------------------------------------------------------------------
extern "C" void kernel_launch(void* const* d_in, const int* in_sizes, int n_in,
                              void* d_out, int out_size, void* d_ws,
                              size_t ws_size, hipStream_t stream) {
  const float* tokens = (const float*)d_in[0];
  const float* span_w = (const float*)d_in[1];
  const float* span_b = (const float*)d_in[2];
  const float* prefix_w = (const float*)d_in[3];
  const float* prefix_b = (const float*)d_in[4];
  const float* suffix_w = (const float*)d_in[5];
  const float* suffix_b = (const float*)d_in[6];
  const float* fc_w = (const float*)d_in[7];
  const float* fc_b = (const float*)d_in[8];
  const int* spans = (const int*)d_in[9];
  const int* wsl = (const int*)d_in[10];
  float* out = (float*)d_out;

  char* ws = (char*)d_ws;
  float* Ct = (float*)ws;                     // 1152*4096*4 = 18874368
  _Float16* A2 = (_Float16*)(ws + 18874368);  // 4096*2304*2 = 18874368
  _Float16* Bt = (_Float16*)(ws + 37748736);  // 1152*2304*2 =  5308416
  float* PM2 = (float*)(ws + 43057152);       // 2097152
  float* SM2 = (float*)(ws + 45154304);       // 2097152
  float* fcT = (float*)(ws + 47251456);       // 98304

  hipLaunchKernelGGL(prep, dim3(3312), dim3(256), 0, stream, tokens, span_w,
                     prefix_w, suffix_w, fc_w, A2, Bt, fcT);
  hipLaunchKernelGGL(gemm_f16, dim3(32, 9), dim3(512), 0, stream, A2, Bt, Ct);
  hipLaunchKernelGGL(scan_kernel, dim3(256), dim3(256), 0, stream, Ct, wsl,
                     PM2, SM2);
  hipLaunchKernelGGL(span_kernel, dim3(256), dim3(128), 0, stream, Ct, PM2,
                     SM2, prefix_b, span_b, suffix_b, fcT, fc_b, spans, wsl,
                     out);
}

// Round 8
// 149.297 us; speedup vs baseline: 3.2281x; 1.0259x over previous
//
#include <hip/hip_runtime.h>
#include <hip/hip_bf16.h>
#include <math.h>

// B=8, N=32, S=512, H=768, K=3, C=128, L=64, W=16
#define NEG_INF (-1e30f)

typedef _Float16 half8 __attribute__((ext_vector_type(8)));
typedef _Float16 half4 __attribute__((ext_vector_type(4)));
typedef float f32x4 __attribute__((ext_vector_type(4)));

__device__ __forceinline__ void load_lds16(const void* g, void* l) {
  __builtin_amdgcn_global_load_lds((const __attribute__((address_space(1))) void*)g,
                                   (__attribute__((address_space(3))) void*)l, 16, 0, 0);
}

// ---------------------------------------------------------------------------
// Kernel 1 (prep): 2-plane split (K=1536, 2x expansion not 3x):
//   A2 [4096 x 1536] f16 = [A_hi | A_lo*2^6]
//   Bt [1152 x 1536] f16 (j-major) = [B_hi | B_lo*2^6]
//   exact identity: a*b = ah*bh + 2^-6*((al*2^6)*bh + ah*(bl*2^6)) - al*bl
//   (dropped al*bl ~ 2^-22 relative; 2^-6 applied in fp32 epilogue, exact)
//   fcT[i][c] fp32
// ---------------------------------------------------------------------------
__global__ __launch_bounds__(256) void prep(
    const float* __restrict__ tokens, const float* __restrict__ span_w,
    const float* __restrict__ prefix_w, const float* __restrict__ suffix_w,
    const float* __restrict__ fc_w, _Float16* __restrict__ A2,
    _Float16* __restrict__ Bt, float* __restrict__ fcT) {
  int bid = blockIdx.x;
  int t = threadIdx.x;
  if (bid < 3072) {  // A2: 4 consecutive h per thread
    int g4 = (bid * 256 + t) * 4;
    int m = g4 / 768, h = g4 % 768;
    float4 x = *(const float4*)(tokens + g4);
    float xs[4] = {x.x, x.y, x.z, x.w};
    half4 hi, lo;
#pragma unroll
    for (int i = 0; i < 4; ++i) {
      _Float16 h_ = (_Float16)xs[i];
      hi[i] = h_;
      lo[i] = (_Float16)((xs[i] - (float)h_) * 64.0f);
    }
    size_t base = (size_t)m * 1536 + h;
    *(half4*)(A2 + base) = hi;
    *(half4*)(A2 + base + 768) = lo;
  } else if (bid < 3216) {  // Bt: 8 h x 3 taps per thread
    int g = (bid - 3072) * 256 + t;  // over 3*128*96 = 36864
    int ws = g / 12288;
    int r = g % 12288;
    int c = r / 96, h = (r % 96) * 8;
    const float* wsrc = (ws == 0) ? prefix_w : (ws == 1) ? span_w : suffix_w;
    const float* src = wsrc + (size_t)(c * 768 + h) * 3;
    float wv[24];
#pragma unroll
    for (int i = 0; i < 6; ++i) *(float4*)&wv[i * 4] = *(const float4*)(src + i * 4);
#pragma unroll
    for (int tap = 0; tap < 3; ++tap) {
      half8 hi, lo;
#pragma unroll
      for (int i = 0; i < 8; ++i) {
        float x = wv[i * 3 + tap];
        _Float16 h_ = (_Float16)x;
        hi[i] = h_;
        lo[i] = (_Float16)((x - (float)h_) * 64.0f);
      }
      size_t jb = (size_t)(ws * 384 + tap * 128 + c) * 1536 + h;
      *(half8*)(Bt + jb) = hi;
      *(half8*)(Bt + jb + 768) = lo;
    }
  } else {  // fcT
    int g = (bid - 3216) * 256 + t;
    int i = g >> 6, c = g & 63;
    fcT[g] = fc_w[c * 384 + i];
  }
}

// ---------------------------------------------------------------------------
// Kernel 2: MFMA GEMM  Ct[j][m] = acc_a + 2^-6 * acc_b  where per k:
//   acc_a += A0*B0 ; acc_b += A1*B0 + A0*B1   (planes 0/1 of each operand)
//   M=4096, N=1152, Kplane=768. BM=64, BN=128, 256 thr (4 waves),
//   wave-tile 32x64. Per iter: 32 k-elems of BOTH planes staged per row
//   (row = 64 halfs = [p0 k..k+31 | p1 k..k+31]), 24 iters.
//   r5 skeleton: global_load_lds + double-buffer + 1 barrier/iter +
//   XOR source-chunk swizzle (conflict-free, measured r5).
//   A0/B0 frags feed 2 MFMAs each -> 24 MFMA per 12 ds_read_b128:
//   32.8 FLOP/LDS-byte vs r7's 21.3.
// ---------------------------------------------------------------------------
__global__ __launch_bounds__(256) void gemm_f16(const _Float16* __restrict__ A2,
                                                const _Float16* __restrict__ Bt,
                                                float* __restrict__ Ct) {
  __shared__ _Float16 As[2][64 * 64];   // 2 x 8 KB
  __shared__ _Float16 Bs[2][128 * 64];  // 2 x 16 KB
  const int bm = blockIdx.x * 64;
  const int bj = blockIdx.y * 128;
  const int tid = threadIdx.x;
  const int w = tid >> 6;
  const int lane = tid & 63;
  // staging: lane -> (local row lr, swizzled chunk kcs); chunk 0-3 = plane0,
  // 4-7 = plane1 (source element offset (kcs>>2)*768 + (kcs&3)*8)
  const int lr = lane >> 3;
  const int kcs = (lane & 7) ^ lr;
  const int srcoff = (kcs >> 2) * 768 + (kcs & 3) * 8;
  const _Float16* gA = A2 + (size_t)(bm + w * 8 + lr) * 1536 + srcoff;
  const _Float16* gB = Bt + (size_t)(bj + w * 8 + lr) * 1536 + srcoff;
  // fragment read constants
  const int mrow = lane & 15;
  const int q = lane >> 4;
  const int m0w = (w & 1) * 32;
  const int n0w = (w >> 1) * 64;
  const int sw8 = mrow & 7;
  const int coA0 = (q ^ sw8) * 8;        // plane0 logical chunk q
  const int coA1 = ((q + 4) ^ sw8) * 8;  // plane1 logical chunk 4+q
  f32x4 aa[2][4], ab[2][4];
#pragma unroll
  for (int i = 0; i < 2; ++i)
#pragma unroll
    for (int j = 0; j < 4; ++j) {
      aa[i][j] = (f32x4){0.f, 0.f, 0.f, 0.f};
      ab[i][j] = (f32x4){0.f, 0.f, 0.f, 0.f};
    }

  // prologue: stage kp=0 into buf0
  load_lds16(gA, &As[0][w * 512]);
  load_lds16(gA + 32 * 1536, &As[0][2048 + w * 512]);
#pragma unroll
  for (int p = 0; p < 4; ++p)
    load_lds16(gB + (size_t)p * 32 * 1536, &Bs[0][p * 2048 + w * 512]);

  for (int i = 0; i < 24; ++i) {
    const int cur = i & 1;
    __syncthreads();  // vmcnt drain: buf cur staged; prev reads done
    if (i + 1 < 24) {
      const int kp = (i + 1) * 32;
      const int nxt = cur ^ 1;
      load_lds16(gA + kp, &As[nxt][w * 512]);
      load_lds16(gA + kp + 32 * 1536, &As[nxt][2048 + w * 512]);
#pragma unroll
      for (int p = 0; p < 4; ++p)
        load_lds16(gB + kp + (size_t)p * 32 * 1536,
                   &Bs[nxt][p * 2048 + w * 512]);
    }
    half8 a00 = *(const half8*)&As[cur][(m0w + mrow) * 64 + coA0];
    half8 a01 = *(const half8*)&As[cur][(m0w + 16 + mrow) * 64 + coA0];
    half8 a10 = *(const half8*)&As[cur][(m0w + mrow) * 64 + coA1];
    half8 a11 = *(const half8*)&As[cur][(m0w + 16 + mrow) * 64 + coA1];
#pragma unroll
    for (int nt = 0; nt < 4; ++nt) {
      half8 b0 = *(const half8*)&Bs[cur][(n0w + nt * 16 + mrow) * 64 + coA0];
      half8 b1 = *(const half8*)&Bs[cur][(n0w + nt * 16 + mrow) * 64 + coA1];
      aa[0][nt] = __builtin_amdgcn_mfma_f32_16x16x32_f16(a00, b0, aa[0][nt], 0, 0, 0);
      aa[1][nt] = __builtin_amdgcn_mfma_f32_16x16x32_f16(a01, b0, aa[1][nt], 0, 0, 0);
      ab[0][nt] = __builtin_amdgcn_mfma_f32_16x16x32_f16(a10, b0, ab[0][nt], 0, 0, 0);
      ab[1][nt] = __builtin_amdgcn_mfma_f32_16x16x32_f16(a11, b0, ab[1][nt], 0, 0, 0);
      ab[0][nt] = __builtin_amdgcn_mfma_f32_16x16x32_f16(a00, b1, ab[0][nt], 0, 0, 0);
      ab[1][nt] = __builtin_amdgcn_mfma_f32_16x16x32_f16(a01, b1, ab[1][nt], 0, 0, 0);
    }
  }
  // C/D layout: m = (lane>>4)*4 + reg, n = lane&15
  const int mbase = bm + m0w + q * 4;
#pragma unroll
  for (int mt = 0; mt < 2; ++mt)
#pragma unroll
    for (int nt = 0; nt < 4; ++nt) {
      int n_out = bj + n0w + nt * 16 + mrow;
      f32x4 v = aa[mt][nt] + 0.015625f * ab[mt][nt];
      *(f32x4*)(Ct + (size_t)n_out * 4096 + mbase + mt * 16) = v;
    }
}

// ---------------------------------------------------------------------------
// Kernel 3: per-(b,c) tap-combine + prefix-max / suffix-max scans
// ---------------------------------------------------------------------------
__global__ __launch_bounds__(256) void scan_kernel(const float* __restrict__ Ct,
                                                   const int* __restrict__ wsl,
                                                   float* __restrict__ PM2,
                                                   float* __restrict__ SM2) {
  int pair = blockIdx.x * 4 + (threadIdx.x >> 6);
  int b = pair >> 7;
  int c = pair & 127;
  int lane = threadIdx.x & 63;
  int mb = b * 512;
  int t0 = lane * 8;
  const float* p0 = Ct + (size_t)(0 + c) * 4096 + mb;
  const float* p1 = Ct + (size_t)(128 + c) * 4096 + mb;
  const float* p2 = Ct + (size_t)(256 + c) * 4096 + mb;
  float v[8];
#pragma unroll
  for (int i = 0; i < 8; i++) {
    int t = t0 + i;
    v[i] = (t < 494) ? (p0[t] + p1[t + 1] + p2[t + 2]) : NEG_INF;
  }
#pragma unroll
  for (int i = 1; i < 8; i++) v[i] = fmaxf(v[i], v[i - 1]);
  float x = v[7];
#pragma unroll
  for (int d = 1; d < 64; d <<= 1) {
    float y = __shfl_up(x, d);
    if (lane >= d) x = fmaxf(x, y);
  }
  float excl = __shfl_up(x, 1);
  if (lane == 0) excl = NEG_INF;
  float* pm = PM2 + (size_t)pair * 512;
#pragma unroll
  for (int i = 0; i < 8; i++) {
    int t = t0 + i;
    if (t < 494) pm[t] = fmaxf(v[i], excl);
  }
  const float* s0 = Ct + (size_t)(768 + c) * 4096 + mb;
  const float* s1 = Ct + (size_t)(896 + c) * 4096 + mb;
  const float* s2 = Ct + (size_t)(1024 + c) * 4096 + mb;
  int qmax = wsl[b] - 3;
  if (qmax > 509) qmax = 509;
  float u[8];
#pragma unroll
  for (int i = 0; i < 8; i++) {
    int q = t0 + i;
    u[i] = (q <= qmax) ? (s0[q] + s1[q + 1] + s2[q + 2]) : NEG_INF;
  }
#pragma unroll
  for (int i = 6; i >= 0; i--) u[i] = fmaxf(u[i], u[i + 1]);
  float xr = u[0];
#pragma unroll
  for (int d = 1; d < 64; d <<= 1) {
    float y = __shfl_down(xr, d);
    if (lane < 64 - d) xr = fmaxf(xr, y);
  }
  float exclr = __shfl_down(xr, 1);
  if (lane == 63) exclr = NEG_INF;
  float* sm = SM2 + (size_t)pair * 512;
#pragma unroll
  for (int i = 0; i < 8; i++) sm[t0 + i] = fmaxf(u[i], exclr);
}

// ---------------------------------------------------------------------------
// Kernel 4: per-span features + coalesced FC + sigmoid + threshold
// ---------------------------------------------------------------------------
__global__ __launch_bounds__(128) void span_kernel(
    const float* __restrict__ Ct, const float* __restrict__ PM2,
    const float* __restrict__ SM2, const float* __restrict__ prefix_b,
    const float* __restrict__ span_b, const float* __restrict__ suffix_b,
    const float* __restrict__ fcT, const float* __restrict__ fc_b,
    const int* __restrict__ spans, const int* __restrict__ wsl,
    float* __restrict__ out) {
  __shared__ float sfeat[384];
  __shared__ float part[64];
  int sp = blockIdx.x;
  int b = sp >> 5;
  int c = threadIdx.x;
  int s = spans[sp * 2], e = spans[sp * 2 + 1];
  int Lb = wsl[b];
  int mb = b * 512;
  {  // prefix (T=496)
    const float* t0p = Ct + (size_t)c * 4096 + mb;
    const float* t1p = Ct + (size_t)(128 + c) * 4096 + mb;
    float m = NEG_INF;
    if (s >= 3) m = fmaxf(m, PM2[(size_t)(b * 128 + c) * 512 + s - 3]);
    if (s >= 2 && s <= 495) m = fmaxf(m, t0p[s - 2] + t1p[s - 1]);
    if (s >= 1 && s <= 494) m = fmaxf(m, t0p[s - 1]);
    if (s <= 493) m = fmaxf(m, 0.0f);
    sfeat[c] = m + prefix_b[c];
  }
  {  // span (T=16)
    const float* u0 = Ct + (size_t)(384 + c) * 4096 + mb;
    const float* u1 = Ct + (size_t)(512 + c) * 4096 + mb;
    const float* u2 = Ct + (size_t)(640 + c) * 4096 + mb;
    int w = e - s;
    float m = NEG_INF;
    for (int p = 0; p + 2 < w; ++p)
      m = fmaxf(m, u0[s + p] + u1[s + p + 1] + u2[s + p + 2]);
    if (w >= 2 && w <= 15) m = fmaxf(m, u0[s + w - 2] + u1[s + w - 1]);
    if (w <= 14) m = fmaxf(m, u0[s + w - 1]);
    if (w <= 13) m = fmaxf(m, 0.0f);
    sfeat[128 + c] = m + span_b[c];
  }
  {  // suffix (T=511)
    const float* x0 = Ct + (size_t)(768 + c) * 4096 + mb;
    const float* x1 = Ct + (size_t)(896 + c) * 4096 + mb;
    float m = NEG_INF;
    if (e <= Lb - 3) m = fmaxf(m, SM2[(size_t)(b * 128 + c) * 512 + e]);
    if (Lb - 2 - e >= 0 && Lb - 2 - e <= 508)
      m = fmaxf(m, x0[Lb - 2] + x1[Lb - 1]);
    if (Lb - 1 - e >= 0 && Lb - 1 - e <= 508) m = fmaxf(m, x0[Lb - 1]);
    if (Lb - e <= 508) m = fmaxf(m, 0.0f);
    sfeat[256 + c] = m + suffix_b[c];
  }
  __syncthreads();
  {
    int cc = threadIdx.x & 63;
    int half = threadIdx.x >> 6;
    float acc2 = 0.0f;
    const float* fp = fcT + (size_t)(half * 192) * 64 + cc;
    const float* sf = sfeat + half * 192;
#pragma unroll 8
    for (int i = 0; i < 192; ++i) acc2 = fmaf(sf[i], fp[(size_t)i * 64], acc2);
    if (half) part[cc] = acc2;
    __syncthreads();
    if (!half) {
      float a = acc2 + part[cc] + fc_b[cc];
      float pr = 1.0f / (1.0f + expf(-a));
      out[sp * 64 + cc] = pr;
      out[16384 + sp * 64 + cc] = (pr > 0.5f) ? 1.0f : 0.0f;
    }
  }
}

// ---------------------------------------------------------------------------
extern "C" void kernel_launch(void* const* d_in, const int* in_sizes, int n_in,
                              void* d_out, int out_size, void* d_ws,
                              size_t ws_size, hipStream_t stream) {
  const float* tokens = (const float*)d_in[0];
  const float* span_w = (const float*)d_in[1];
  const float* span_b = (const float*)d_in[2];
  const float* prefix_w = (const float*)d_in[3];
  const float* prefix_b = (const float*)d_in[4];
  const float* suffix_w = (const float*)d_in[5];
  const float* suffix_b = (const float*)d_in[6];
  const float* fc_w = (const float*)d_in[7];
  const float* fc_b = (const float*)d_in[8];
  const int* spans = (const int*)d_in[9];
  const int* wsl = (const int*)d_in[10];
  float* out = (float*)d_out;

  char* ws = (char*)d_ws;
  float* Ct = (float*)ws;                     // 1152*4096*4 = 18874368
  _Float16* A2 = (_Float16*)(ws + 18874368);  // 4096*1536*2 = 12582912
  _Float16* Bt = (_Float16*)(ws + 31457280);  // 1152*1536*2 =  3538944
  float* PM2 = (float*)(ws + 34996224);       // 2097152
  float* SM2 = (float*)(ws + 37093376);       // 2097152
  float* fcT = (float*)(ws + 39190528);       // 98304  (total 39.3 MB)

  hipLaunchKernelGGL(prep, dim3(3312), dim3(256), 0, stream, tokens, span_w,
                     prefix_w, suffix_w, fc_w, A2, Bt, fcT);
  hipLaunchKernelGGL(gemm_f16, dim3(64, 9), dim3(256), 0, stream, A2, Bt, Ct);
  hipLaunchKernelGGL(scan_kernel, dim3(256), dim3(256), 0, stream, Ct, wsl,
                     PM2, SM2);
  hipLaunchKernelGGL(span_kernel, dim3(256), dim3(128), 0, stream, Ct, PM2,
                     SM2, prefix_b, span_b, suffix_b, fcT, fc_b, spans, wsl,
                     out);
}

// Round 9
// 147.640 us; speedup vs baseline: 3.2644x; 1.0112x over previous
//
#include <hip/hip_runtime.h>
#include <hip/hip_bf16.h>
#include <math.h>

// B=8, N=32, S=512, H=768, K=3, C=128, L=64, W=16
#define NEG_INF (-1e30f)

typedef _Float16 half8 __attribute__((ext_vector_type(8)));
typedef _Float16 half4 __attribute__((ext_vector_type(4)));
typedef float f32x4 __attribute__((ext_vector_type(4)));
typedef float f32x16 __attribute__((ext_vector_type(16)));

__device__ __forceinline__ void load_lds16(const void* g, void* l) {
  __builtin_amdgcn_global_load_lds((const __attribute__((address_space(1))) void*)g,
                                   (__attribute__((address_space(3))) void*)l, 16, 0, 0);
}

// ---------------------------------------------------------------------------
// Kernel 1 (prep): 2-plane split (K=1536):
//   A2 [4096 x 1536] f16 = [A_hi | A_lo*2^6]
//   Bt [1152 x 1536] f16 (j-major) = [B_hi | B_lo*2^6]
//   fcT[i][c] fp32
// ---------------------------------------------------------------------------
__global__ __launch_bounds__(256) void prep(
    const float* __restrict__ tokens, const float* __restrict__ span_w,
    const float* __restrict__ prefix_w, const float* __restrict__ suffix_w,
    const float* __restrict__ fc_w, _Float16* __restrict__ A2,
    _Float16* __restrict__ Bt, float* __restrict__ fcT) {
  int bid = blockIdx.x;
  int t = threadIdx.x;
  if (bid < 3072) {  // A2
    int g4 = (bid * 256 + t) * 4;
    int m = g4 / 768, h = g4 % 768;
    float4 x = *(const float4*)(tokens + g4);
    float xs[4] = {x.x, x.y, x.z, x.w};
    half4 hi, lo;
#pragma unroll
    for (int i = 0; i < 4; ++i) {
      _Float16 h_ = (_Float16)xs[i];
      hi[i] = h_;
      lo[i] = (_Float16)((xs[i] - (float)h_) * 64.0f);
    }
    size_t base = (size_t)m * 1536 + h;
    *(half4*)(A2 + base) = hi;
    *(half4*)(A2 + base + 768) = lo;
  } else if (bid < 3216) {  // Bt
    int g = (bid - 3072) * 256 + t;  // over 3*128*96 = 36864
    int ws = g / 12288;
    int r = g % 12288;
    int c = r / 96, h = (r % 96) * 8;
    const float* wsrc = (ws == 0) ? prefix_w : (ws == 1) ? span_w : suffix_w;
    const float* src = wsrc + (size_t)(c * 768 + h) * 3;
    float wv[24];
#pragma unroll
    for (int i = 0; i < 6; ++i) *(float4*)&wv[i * 4] = *(const float4*)(src + i * 4);
#pragma unroll
    for (int tap = 0; tap < 3; ++tap) {
      half8 hi, lo;
#pragma unroll
      for (int i = 0; i < 8; ++i) {
        float x = wv[i * 3 + tap];
        _Float16 h_ = (_Float16)x;
        hi[i] = h_;
        lo[i] = (_Float16)((x - (float)h_) * 64.0f);
      }
      size_t jb = (size_t)(ws * 384 + tap * 128 + c) * 1536 + h;
      *(half8*)(Bt + jb) = hi;
      *(half8*)(Bt + jb + 768) = lo;
    }
  } else {  // fcT
    int g = (bid - 3216) * 256 + t;
    int i = g >> 6, c = g & 63;
    fcT[g] = fc_w[c * 384 + i];
  }
}

// ---------------------------------------------------------------------------
// Kernel 2: MFMA GEMM with mfma_f32_32x32x16_f16 (2x FLOP/instr vs 16x16x32).
//   Ct[j][m] = aa + 2^-6 * ab;  per k16: aa += A0*B0; ab += A1*B0 + A0*B1.
//   M=4096, N=1152, Kplane=768. BM=128, BN=64, BK=32, 512 thr (8 waves),
//   wave-tile 32x32 -> acc only 32 VGPR -> high occupancy (3 blocks/CU by
//   48 KB LDS, ~5 waves/SIMD by VGPR). Grid (32,18)=576.
//   LDS row = 64 halfs = [p0 k0..31 | p1 k0..31], 16B chunks XOR-swizzled by
//   row&7 (conflict-free, verified r5/r8). glds staging, dbuf, 1 barrier/iter.
// ---------------------------------------------------------------------------
__global__ __launch_bounds__(512) void gemm_f16(const _Float16* __restrict__ A2,
                                                const _Float16* __restrict__ Bt,
                                                float* __restrict__ Ct) {
  __shared__ _Float16 As[2][128 * 64];  // 2 x 16 KB
  __shared__ _Float16 Bs[2][64 * 64];   // 2 x 8 KB
  const int bm = blockIdx.x * 128;
  const int bj = blockIdx.y * 64;
  const int tid = threadIdx.x;
  const int w = tid >> 6;
  const int lane = tid & 63;
  // staging: each glds covers 8 rows x 8 chunks (1024 B); lane -> (lrow, cphys)
  const int lrow = lane >> 3;
  const int cphys = lane & 7;
  const int clog = cphys ^ (lrow & 7);
  const int srcoff = (clog >> 2) * 768 + (clog & 3) * 8;  // plane + k-sub
  const _Float16* gA0 = A2 + (size_t)(bm + w * 16 + lrow) * 1536 + srcoff;
  const _Float16* gA1 = A2 + (size_t)(bm + w * 16 + 8 + lrow) * 1536 + srcoff;
  const _Float16* gB0 = Bt + (size_t)(bj + w * 8 + lrow) * 1536 + srcoff;
  // fragment read constants (32x32x16: m/n = lane&31, k = (lane>>5)*8 + j)
  const int m0w = (w & 3) * 32;
  const int n0w = (w >> 2) * 32;
  const int arow = m0w + (lane & 31);
  const int brow = n0w + (lane & 31);
  const int hi32 = lane >> 5;
  const int sw = lane & 7;  // arow&7 == brow&7 == lane&7
#define CO(p, ks) (((((p) * 4 + (ks) * 2 + hi32)) ^ sw) * 8)
  f32x16 aa, ab;
#pragma unroll
  for (int q = 0; q < 16; ++q) {
    aa[q] = 0.f;
    ab[q] = 0.f;
  }
  // prologue: stage iter 0 into buf 0
  load_lds16(gA0, &As[0][w * 1024]);
  load_lds16(gA1, &As[0][w * 1024 + 512]);
  load_lds16(gB0, &Bs[0][w * 512]);

  for (int i = 0; i < 24; ++i) {
    const int cur = i & 1;
    __syncthreads();  // buf cur staged; prev iter's reads done
    if (i + 1 < 24) {
      const int kp = (i + 1) * 32;
      const int nxt = cur ^ 1;
      load_lds16(gA0 + kp, &As[nxt][w * 1024]);
      load_lds16(gA1 + kp, &As[nxt][w * 1024 + 512]);
      load_lds16(gB0 + kp, &Bs[nxt][w * 512]);
    }
#pragma unroll
    for (int ks = 0; ks < 2; ++ks) {
      half8 a0 = *(const half8*)&As[cur][arow * 64 + CO(0, ks)];
      half8 a1 = *(const half8*)&As[cur][arow * 64 + CO(1, ks)];
      half8 b0 = *(const half8*)&Bs[cur][brow * 64 + CO(0, ks)];
      half8 b1 = *(const half8*)&Bs[cur][brow * 64 + CO(1, ks)];
      aa = __builtin_amdgcn_mfma_f32_32x32x16_f16(a0, b0, aa, 0, 0, 0);
      ab = __builtin_amdgcn_mfma_f32_32x32x16_f16(a1, b0, ab, 0, 0, 0);
      ab = __builtin_amdgcn_mfma_f32_32x32x16_f16(a0, b1, ab, 0, 0, 0);
    }
  }
#undef CO
  // C/D layout (m74/m101): col(n)=lane&31, row(m)=(reg&3)+8*(reg>>2)+4*(lane>>5)
  const int n_out = bj + n0w + (lane & 31);
  float* cp = Ct + (size_t)n_out * 4096 + bm + m0w + 4 * hi32;
#pragma unroll
  for (int r = 0; r < 4; ++r) {
    f32x4 v;
#pragma unroll
    for (int q = 0; q < 4; ++q) v[q] = aa[4 * r + q] + 0.015625f * ab[4 * r + q];
    *(f32x4*)(cp + 8 * r) = v;
  }
}

// ---------------------------------------------------------------------------
// Kernel 3: per-(b,c) tap-combine + prefix-max / suffix-max scans
// ---------------------------------------------------------------------------
__global__ __launch_bounds__(256) void scan_kernel(const float* __restrict__ Ct,
                                                   const int* __restrict__ wsl,
                                                   float* __restrict__ PM2,
                                                   float* __restrict__ SM2) {
  int pair = blockIdx.x * 4 + (threadIdx.x >> 6);
  int b = pair >> 7;
  int c = pair & 127;
  int lane = threadIdx.x & 63;
  int mb = b * 512;
  int t0 = lane * 8;
  const float* p0 = Ct + (size_t)(0 + c) * 4096 + mb;
  const float* p1 = Ct + (size_t)(128 + c) * 4096 + mb;
  const float* p2 = Ct + (size_t)(256 + c) * 4096 + mb;
  float v[8];
#pragma unroll
  for (int i = 0; i < 8; i++) {
    int t = t0 + i;
    v[i] = (t < 494) ? (p0[t] + p1[t + 1] + p2[t + 2]) : NEG_INF;
  }
#pragma unroll
  for (int i = 1; i < 8; i++) v[i] = fmaxf(v[i], v[i - 1]);
  float x = v[7];
#pragma unroll
  for (int d = 1; d < 64; d <<= 1) {
    float y = __shfl_up(x, d);
    if (lane >= d) x = fmaxf(x, y);
  }
  float excl = __shfl_up(x, 1);
  if (lane == 0) excl = NEG_INF;
  float* pm = PM2 + (size_t)pair * 512;
#pragma unroll
  for (int i = 0; i < 8; i++) {
    int t = t0 + i;
    if (t < 494) pm[t] = fmaxf(v[i], excl);
  }
  const float* s0 = Ct + (size_t)(768 + c) * 4096 + mb;
  const float* s1 = Ct + (size_t)(896 + c) * 4096 + mb;
  const float* s2 = Ct + (size_t)(1024 + c) * 4096 + mb;
  int qmax = wsl[b] - 3;
  if (qmax > 509) qmax = 509;
  float u[8];
#pragma unroll
  for (int i = 0; i < 8; i++) {
    int q = t0 + i;
    u[i] = (q <= qmax) ? (s0[q] + s1[q + 1] + s2[q + 2]) : NEG_INF;
  }
#pragma unroll
  for (int i = 6; i >= 0; i--) u[i] = fmaxf(u[i], u[i + 1]);
  float xr = u[0];
#pragma unroll
  for (int d = 1; d < 64; d <<= 1) {
    float y = __shfl_down(xr, d);
    if (lane < 64 - d) xr = fmaxf(xr, y);
  }
  float exclr = __shfl_down(xr, 1);
  if (lane == 63) exclr = NEG_INF;
  float* sm = SM2 + (size_t)pair * 512;
#pragma unroll
  for (int i = 0; i < 8; i++) sm[t0 + i] = fmaxf(u[i], exclr);
}

// ---------------------------------------------------------------------------
// Kernel 4: per-span features + coalesced FC + sigmoid + threshold
// ---------------------------------------------------------------------------
__global__ __launch_bounds__(128) void span_kernel(
    const float* __restrict__ Ct, const float* __restrict__ PM2,
    const float* __restrict__ SM2, const float* __restrict__ prefix_b,
    const float* __restrict__ span_b, const float* __restrict__ suffix_b,
    const float* __restrict__ fcT, const float* __restrict__ fc_b,
    const int* __restrict__ spans, const int* __restrict__ wsl,
    float* __restrict__ out) {
  __shared__ float sfeat[384];
  __shared__ float part[64];
  int sp = blockIdx.x;
  int b = sp >> 5;
  int c = threadIdx.x;
  int s = spans[sp * 2], e = spans[sp * 2 + 1];
  int Lb = wsl[b];
  int mb = b * 512;
  {  // prefix (T=496)
    const float* t0p = Ct + (size_t)c * 4096 + mb;
    const float* t1p = Ct + (size_t)(128 + c) * 4096 + mb;
    float m = NEG_INF;
    if (s >= 3) m = fmaxf(m, PM2[(size_t)(b * 128 + c) * 512 + s - 3]);
    if (s >= 2 && s <= 495) m = fmaxf(m, t0p[s - 2] + t1p[s - 1]);
    if (s >= 1 && s <= 494) m = fmaxf(m, t0p[s - 1]);
    if (s <= 493) m = fmaxf(m, 0.0f);
    sfeat[c] = m + prefix_b[c];
  }
  {  // span (T=16)
    const float* u0 = Ct + (size_t)(384 + c) * 4096 + mb;
    const float* u1 = Ct + (size_t)(512 + c) * 4096 + mb;
    const float* u2 = Ct + (size_t)(640 + c) * 4096 + mb;
    int w = e - s;
    float m = NEG_INF;
    for (int p = 0; p + 2 < w; ++p)
      m = fmaxf(m, u0[s + p] + u1[s + p + 1] + u2[s + p + 2]);
    if (w >= 2 && w <= 15) m = fmaxf(m, u0[s + w - 2] + u1[s + w - 1]);
    if (w <= 14) m = fmaxf(m, u0[s + w - 1]);
    if (w <= 13) m = fmaxf(m, 0.0f);
    sfeat[128 + c] = m + span_b[c];
  }
  {  // suffix (T=511)
    const float* x0 = Ct + (size_t)(768 + c) * 4096 + mb;
    const float* x1 = Ct + (size_t)(896 + c) * 4096 + mb;
    float m = NEG_INF;
    if (e <= Lb - 3) m = fmaxf(m, SM2[(size_t)(b * 128 + c) * 512 + e]);
    if (Lb - 2 - e >= 0 && Lb - 2 - e <= 508)
      m = fmaxf(m, x0[Lb - 2] + x1[Lb - 1]);
    if (Lb - 1 - e >= 0 && Lb - 1 - e <= 508) m = fmaxf(m, x0[Lb - 1]);
    if (Lb - e <= 508) m = fmaxf(m, 0.0f);
    sfeat[256 + c] = m + suffix_b[c];
  }
  __syncthreads();
  {
    int cc = threadIdx.x & 63;
    int half = threadIdx.x >> 6;
    float acc2 = 0.0f;
    const float* fp = fcT + (size_t)(half * 192) * 64 + cc;
    const float* sf = sfeat + half * 192;
#pragma unroll 8
    for (int i = 0; i < 192; ++i) acc2 = fmaf(sf[i], fp[(size_t)i * 64], acc2);
    if (half) part[cc] = acc2;
    __syncthreads();
    if (!half) {
      float a = acc2 + part[cc] + fc_b[cc];
      float pr = 1.0f / (1.0f + expf(-a));
      out[sp * 64 + cc] = pr;
      out[16384 + sp * 64 + cc] = (pr > 0.5f) ? 1.0f : 0.0f;
    }
  }
}

// ---------------------------------------------------------------------------
extern "C" void kernel_launch(void* const* d_in, const int* in_sizes, int n_in,
                              void* d_out, int out_size, void* d_ws,
                              size_t ws_size, hipStream_t stream) {
  const float* tokens = (const float*)d_in[0];
  const float* span_w = (const float*)d_in[1];
  const float* span_b = (const float*)d_in[2];
  const float* prefix_w = (const float*)d_in[3];
  const float* prefix_b = (const float*)d_in[4];
  const float* suffix_w = (const float*)d_in[5];
  const float* suffix_b = (const float*)d_in[6];
  const float* fc_w = (const float*)d_in[7];
  const float* fc_b = (const float*)d_in[8];
  const int* spans = (const int*)d_in[9];
  const int* wsl = (const int*)d_in[10];
  float* out = (float*)d_out;

  char* ws = (char*)d_ws;
  float* Ct = (float*)ws;                     // 1152*4096*4 = 18874368
  _Float16* A2 = (_Float16*)(ws + 18874368);  // 4096*1536*2 = 12582912
  _Float16* Bt = (_Float16*)(ws + 31457280);  // 1152*1536*2 =  3538944
  float* PM2 = (float*)(ws + 34996224);       // 2097152
  float* SM2 = (float*)(ws + 37093376);       // 2097152
  float* fcT = (float*)(ws + 39190528);       // 98304

  hipLaunchKernelGGL(prep, dim3(3312), dim3(256), 0, stream, tokens, span_w,
                     prefix_w, suffix_w, fc_w, A2, Bt, fcT);
  hipLaunchKernelGGL(gemm_f16, dim3(32, 18), dim3(512), 0, stream, A2, Bt, Ct);
  hipLaunchKernelGGL(scan_kernel, dim3(256), dim3(256), 0, stream, Ct, wsl,
                     PM2, SM2);
  hipLaunchKernelGGL(span_kernel, dim3(256), dim3(128), 0, stream, Ct, PM2,
                     SM2, prefix_b, span_b, suffix_b, fcT, fc_b, spans, wsl,
                     out);
}